// Round 3
// baseline (423.928 us; speedup 1.0000x reference)
//
#include <hip/hip_runtime.h>
#include <hip/hip_bf16.h>

#define BH   64
#define LSEQ 8192
#define DDIM 64
#define NPOS (BH * LSEQ)          // 524288 positions
#define NT4  (NPOS * DDIM / 4)    // 8388608 float4s in v/out

typedef __attribute__((ext_vector_type(8))) short bf16x8;
typedef __attribute__((ext_vector_type(4))) float f32x4;

// Native RNE f32->bf16 (compiler can pack pairs into v_cvt_pk_bf16_f32).
__device__ inline short f2bf(float f) {
    __bf16 b = (__bf16)f;
    return __builtin_bit_cast(short, b);
}
__device__ inline float bf2f(short s) {
    unsigned u = ((unsigned)(unsigned short)s) << 16;
    return __builtin_bit_cast(float, u);
}
__device__ inline void split8(const float* f, bf16x8& hi, bf16x8& lo) {
#pragma unroll
    for (int j = 0; j < 8; j++) {
        short h = f2bf(f[j]);
        hi[j] = h;
        lo[j] = f2bf(f[j] - bf2f(h));
    }
}
__device__ inline float tanh_fast(float x) {
    float ex = __expf(2.f * x);
    return 1.f - 2.f * __builtin_amdgcn_rcpf(ex + 1.f);
}

// ---------------------------------------------------------------------------
// K1: e[p] = mask ? va.tanh(Wa q + Ua k + bias) + va_b : -10000
// One wave = 16 positions per tile, 4 tiles/wave, 2-buffer software pipeline.
// sched_barrier(0) fences pin the pipeline so the scheduler cannot sink the
// prefetch loads next to their consumers (previous build: VGPR=100 => the
// pipeline had been flattened and the kernel was load-latency-bound).
// ---------------------------------------------------------------------------
__global__ __launch_bounds__(256, 3) void score_kernel(
    const float* __restrict__ q, const float* __restrict__ k,
    const int*   __restrict__ mask,
    const float* __restrict__ Waw, const float* __restrict__ Wab,
    const float* __restrict__ Uaw, const float* __restrict__ Uab,
    const float* __restrict__ vaw, const float* __restrict__ vab_p,
    float* __restrict__ e_out)
{
    const int lane = threadIdx.x & 63;
    const int m    = lane & 15;
    const int quad = lane >> 4;
    const int wgl  = blockIdx.x * 4 + (threadIdx.x >> 6);
    const long t0  = (long)wgl * 4;

    // per-wave constant weight fragments (bf16), biases, va
    bf16x8 bwa[4][2], bua[4][2];
    float bias_s[4], vav[4];
    float vab;

    float4 A[8], B[8];
    int4 mkA, mkB;

    auto issue = [&](float4 (&buf)[8], int4& mk, long tile) {
        mk = ((const int4*)mask)[tile * 4 + quad];
        const size_t off = (size_t)(tile * 16 + m) * 64 + quad * 8;
        buf[0] = *((const float4*)(q + off));
        buf[1] = *((const float4*)(q + off + 4));
        buf[2] = *((const float4*)(k + off));
        buf[3] = *((const float4*)(k + off + 4));
        buf[4] = *((const float4*)(q + off + 32));
        buf[5] = *((const float4*)(q + off + 36));
        buf[6] = *((const float4*)(k + off + 32));
        buf[7] = *((const float4*)(k + off + 36));
    };

    auto load_weights = [&]() {
#pragma unroll
        for (int t = 0; t < 4; t++) {
            const int n = t * 16 + m;
            bias_s[t] = Wab[n] + Uab[n];
            vav[t]    = vaw[n];
#pragma unroll
            for (int s = 0; s < 2; s++) {
                const int k0 = s * 32 + quad * 8;
                const float4 wA = ((const float4*)(Waw + n * 64 + k0))[0];
                const float4 wB = ((const float4*)(Waw + n * 64 + k0))[1];
                const float4 uA = ((const float4*)(Uaw + n * 64 + k0))[0];
                const float4 uB = ((const float4*)(Uaw + n * 64 + k0))[1];
                float wf[8] = {wA.x, wA.y, wA.z, wA.w, wB.x, wB.y, wB.z, wB.w};
                float uf[8] = {uA.x, uA.y, uA.z, uA.w, uB.x, uB.y, uB.z, uB.w};
                bf16x8 wv, uv;
#pragma unroll
                for (int j = 0; j < 8; j++) { wv[j] = f2bf(wf[j]); uv[j] = f2bf(uf[j]); }
                bwa[t][s] = wv;
                bua[t][s] = uv;
            }
        }
        vab = vab_p[0];
    };

    auto compute = [&](const float4 (&buf)[8], const int4& mk, long tile) {
        f32x4 acc[4];
#pragma unroll
        for (int t = 0; t < 4; t++) acc[t] = (f32x4){0.f, 0.f, 0.f, 0.f};
#pragma unroll
        for (int s = 0; s < 2; s++) {
            const float4 qa = buf[s * 4 + 0], qb = buf[s * 4 + 1];
            const float4 ka = buf[s * 4 + 2], kb = buf[s * 4 + 3];
            float qf[8] = {qa.x, qa.y, qa.z, qa.w, qb.x, qb.y, qb.z, qb.w};
            float kf[8] = {ka.x, ka.y, ka.z, ka.w, kb.x, kb.y, kb.z, kb.w};
            bf16x8 qhi, qlo, khi, klo;
            split8(qf, qhi, qlo);
            split8(kf, khi, klo);
#pragma unroll
            for (int t = 0; t < 4; t++) {
                acc[t] = __builtin_amdgcn_mfma_f32_16x16x32_bf16(qhi, bwa[t][s], acc[t], 0, 0, 0);
                acc[t] = __builtin_amdgcn_mfma_f32_16x16x32_bf16(qlo, bwa[t][s], acc[t], 0, 0, 0);
                acc[t] = __builtin_amdgcn_mfma_f32_16x16x32_bf16(khi, bua[t][s], acc[t], 0, 0, 0);
                acc[t] = __builtin_amdgcn_mfma_f32_16x16x32_bf16(klo, bua[t][s], acc[t], 0, 0, 0);
            }
        }
        float c[4] = {0.f, 0.f, 0.f, 0.f};
#pragma unroll
        for (int t = 0; t < 4; t++) {
#pragma unroll
            for (int r = 0; r < 4; r++)
                c[r] += vav[t] * tanh_fast(acc[t][r] + bias_s[t]);
        }
#pragma unroll
        for (int r = 0; r < 4; r++) {
#pragma unroll
            for (int off2 = 1; off2 < 16; off2 <<= 1)
                c[r] += __shfl_xor(c[r], off2, 16);
        }
        if (m == 0) {
            float4 ev;
            ev.x = mk.x ? c[0] + vab : -10000.f;
            ev.y = mk.y ? c[1] + vab : -10000.f;
            ev.z = mk.z ? c[2] + vab : -10000.f;
            ev.w = mk.w ? c[3] + vab : -10000.f;
            *((float4*)(e_out + tile * 16 + quad * 4)) = ev;
        }
    };

    // Software pipeline: first two tiles' HBM loads go out FIRST, then the
    // (L2-hit) weight prologue hides their latency. sched_barrier(0) after
    // each issue batch stops the scheduler sinking loads into the next
    // compute region (keeps >=1 tile of prefetch distance).
    issue(A, mkA, t0 + 0);
    issue(B, mkB, t0 + 1);
    __builtin_amdgcn_sched_barrier(0);
    load_weights();
    __builtin_amdgcn_sched_barrier(0);
    compute(A, mkA, t0 + 0);
    issue(A, mkA, t0 + 2);
    __builtin_amdgcn_sched_barrier(0);
    compute(B, mkB, t0 + 1);
    issue(B, mkB, t0 + 3);
    __builtin_amdgcn_sched_barrier(0);
    compute(A, mkA, t0 + 2);
    compute(B, mkB, t0 + 3);
}

// ---------------------------------------------------------------------------
// K2: per-row stats: M = max(e), invS = 1/sum(exp(e-M)). Mask already in e.
// ---------------------------------------------------------------------------
__global__ __launch_bounds__(1024) void rowstat_kernel(
    const float* __restrict__ e, float* __restrict__ stats)
{
    const int row = blockIdx.x;
    const size_t base = (size_t)row * LSEQ;
    const int tid  = threadIdx.x;
    const int lane = tid & 63;
    const int wv   = tid >> 6;
    __shared__ float redmax[16];
    __shared__ float redsum[16];

    float4 e0 = ((const float4*)(e + base))[tid];
    float4 e1 = ((const float4*)(e + base))[1024 + tid];
    float em[8] = {e0.x, e0.y, e0.z, e0.w, e1.x, e1.y, e1.z, e1.w};

    float lm = em[0];
#pragma unroll
    for (int j = 1; j < 8; j++) lm = fmaxf(lm, em[j]);
#pragma unroll
    for (int off = 32; off >= 1; off >>= 1) lm = fmaxf(lm, __shfl_xor(lm, off, 64));
    if (lane == 0) redmax[wv] = lm;
    __syncthreads();
    float M = redmax[0];
#pragma unroll
    for (int i = 1; i < 16; i++) M = fmaxf(M, redmax[i]);

    float ls = 0.f;
#pragma unroll
    for (int j = 0; j < 8; j++) ls += __expf(em[j] - M);
#pragma unroll
    for (int off = 32; off >= 1; off >>= 1) ls += __shfl_xor(ls, off, 64);
    if (lane == 0) redsum[wv] = ls;
    __syncthreads();
    if (tid == 0) {
        float S = 0.f;
#pragma unroll
        for (int i = 0; i < 16; i++) S += redsum[i];
        stats[row * 2]     = M;
        stats[row * 2 + 1] = 1.f / S;
    }
}

// ---------------------------------------------------------------------------
// K3: out[p][d] = exp(e[p]-M[row])*invS[row] * v[p][d].
// 4 independent float4 per thread; nontemporal on the 256 MB v/out streams so
// they don't churn L3 (q,k = 256 MB can then stay L3-resident for K1).
// ---------------------------------------------------------------------------
__global__ __launch_bounds__(256) void scale_kernel(
    const float* __restrict__ v, const float* __restrict__ e,
    const float* __restrict__ stats, float* __restrict__ out)
{
    const size_t b0 = (size_t)blockIdx.x * 1024 + threadIdx.x;
    const f32x4* vp = (const f32x4*)v;
    f32x4*       op = (f32x4*)out;

    size_t idx[4];
    f32x4  vv[4];
    float  ee[4];
    float2 st[4];
#pragma unroll
    for (int j = 0; j < 4; j++) {
        idx[j] = b0 + (size_t)j * 256;
        vv[j]  = __builtin_nontemporal_load(vp + idx[j]);
    }
#pragma unroll
    for (int j = 0; j < 4; j++) {
        const size_t p = idx[j] >> 4;
        ee[j] = e[p];
        st[j] = ((const float2*)stats)[p >> 13];
    }
#pragma unroll
    for (int j = 0; j < 4; j++) {
        const float a = __expf(ee[j] - st[j].x) * st[j].y;
        f32x4 o = vv[j] * a;
        __builtin_nontemporal_store(o, op + idx[j]);
    }
}

extern "C" void kernel_launch(void* const* d_in, const int* in_sizes, int n_in,
                              void* d_out, int out_size, void* d_ws, size_t ws_size,
                              hipStream_t stream) {
    const float* q    = (const float*)d_in[0];
    const float* k    = (const float*)d_in[1];
    const float* v    = (const float*)d_in[2];
    const int*   mask = (const int*)d_in[3];
    const float* Waw  = (const float*)d_in[4];
    const float* Wab  = (const float*)d_in[5];
    const float* Uaw  = (const float*)d_in[6];
    const float* Uab  = (const float*)d_in[7];
    const float* vaw  = (const float*)d_in[8];
    const float* vab  = (const float*)d_in[9];
    float* out = (float*)d_out;

    float* e_buf = (float*)d_ws;                  // NPOS floats (2 MB)
    float* stats = (float*)d_ws + NPOS;           // 128 floats (M, invS per row)

    score_kernel<<<2048, 256, 0, stream>>>(q, k, mask, Waw, Wab, Uaw, Uab, vaw, vab, e_buf);
    rowstat_kernel<<<BH, 1024, 0, stream>>>(e_buf, stats);
    scale_kernel<<<NT4 / 1024, 256, 0, stream>>>(v, e_buf, stats, out);
}